// Round 2
// baseline (477.420 us; speedup 1.0000x reference)
//
#include <hip/hip_runtime.h>
#include <hip/hip_bf16.h>

// BiMPM matching, B=32, L=128, H=200, NP=20.
// Input/output dtype (bf16 vs f32) detected at runtime from mask_p[0] bit
// pattern: first u16 == 0x3F80 -> bf16 buffer, == 0x0000 -> f32 buffer
// (mask_p[0] is exactly 1.0 since len_p >= 64). All compute in f32 via ws.
// Output: mv_p (32,128,105) then mv_h (32,128,105).

#define EPSF 1e-8f
#define NEGF -1e7f

constexpr int Bc = 32, Lc = 128, Hc = 200, NPc = 20, NCHc = 105;
constexpr size_t SLH = (size_t)Bc * Lc * Hc;   // 819200
constexpr size_t SLL = (size_t)Bc * Lc * Lc;   // 524288

// workspace layout (floats)
constexpr size_t OFF_CPM    = 0;
constexpr size_t OFF_CHM    = OFF_CPM + SLH;
constexpr size_t OFF_CHMT   = OFF_CHM + SLH;       // [b][h][l]
constexpr size_t OFF_COS    = OFF_CHMT + SLH;      // [b][p][q]
constexpr size_t OFF_COST   = OFF_COS + SLL;       // [b][q][p]
constexpr size_t OFF_AMEANH = OFF_COST + SLL;      // (b,Lp,H)
constexpr size_t OFF_AMAXH  = OFF_AMEANH + SLH;
constexpr size_t OFF_AMEANP = OFF_AMAXH + SLH;     // (b,Lh,H)
constexpr size_t OFF_AMAXP  = OFF_AMEANP + SLH;
constexpr size_t OFF_NORMP  = OFF_AMAXP + SLH;
constexpr size_t OFF_NORMH  = OFF_NORMP + (size_t)Bc * Lc;
constexpr size_t OFF_ROWSUM = OFF_NORMH + (size_t)Bc * Lc;
constexpr size_t OFF_COLSUM = OFF_ROWSUM + (size_t)Bc * Lc;
constexpr size_t OFF_LENP   = OFF_COLSUM + (size_t)Bc * Lc;
constexpr size_t OFF_LENH   = OFF_LENP + Bc;
constexpr size_t OFF_LASTP  = OFF_LENH + Bc;
constexpr size_t OFF_LASTH  = OFF_LASTP + (size_t)Bc * Hc;
constexpr size_t OFF_NWP    = OFF_LASTH + (size_t)Bc * Hc;  // [b][np][l]
constexpr size_t OFF_NWH    = OFF_NWP + (size_t)Bc * NPc * Lc;
// f32 copies of small inputs + dtype flag
constexpr size_t OFF_MASKPF = OFF_NWH + (size_t)Bc * NPc * Lc;
constexpr size_t OFF_MASKHF = OFF_MASKPF + (size_t)Bc * Lc;
constexpr size_t OFF_WFULL  = OFF_MASKHF + (size_t)Bc * Lc;
constexpr size_t OFF_WMP    = OFF_WFULL + (size_t)NPc * Hc;
constexpr size_t OFF_WATT   = OFF_WMP + (size_t)NPc * Hc;
constexpr size_t OFF_WMATT  = OFF_WATT + (size_t)NPc * Hc;
constexpr size_t OFF_FLAG   = OFF_WMATT + (size_t)NPc * Hc;
constexpr size_t WS_FLOATS  = OFF_FLAG + 1;  // ~7.0M floats (~28 MB)

__device__ __forceinline__ float b2f(__hip_bfloat16 x) { return __bfloat162float(x); }

__device__ __forceinline__ float loadf(const void* p, size_t i, int isb) {
  if (isb) return __bfloat162float(((const __hip_bfloat16*)p)[i]);
  return ((const float*)p)[i];
}

__device__ __forceinline__ void storef(void* out, size_t i, float v, int isb) {
  if (isb) ((__hip_bfloat16*)out)[i] = __float2bfloat16(v);
  else ((float*)out)[i] = v;
}

// ---------------- dtype detect + convert small inputs to f32 ----------------
__global__ void convert_kernel(const void* mp, const void* mh, const void* wf,
                               const void* wmp, const void* watt, const void* wma,
                               float* __restrict__ ws) {
  int isb = (((const unsigned short*)mp)[0] == 0x3F80u) ? 1 : 0;
  int g = blockIdx.x * 256 + threadIdx.x;
  if (g == 0) ws[OFF_FLAG] = (float)isb;
  const int n0 = Bc * Lc;          // 4096
  const int nw = NPc * Hc;         // 4000
  if (g < n0) {
    ws[OFF_MASKPF + g] = loadf(mp, g, isb);
  } else if (g < 2 * n0) {
    ws[OFF_MASKHF + (g - n0)] = loadf(mh, g - n0, isb);
  } else {
    int r = g - 2 * n0;
    int seg = r / nw, off = r % nw;
    if (seg == 0) ws[OFF_WFULL + off] = loadf(wf, off, isb);
    else if (seg == 1) ws[OFF_WMP + off] = loadf(wmp, off, isb);
    else if (seg == 2) ws[OFF_WATT + off] = loadf(watt, off, isb);
    else if (seg == 3) ws[OFF_WMATT + off] = loadf(wma, off, isb);
  }
}

// ---------------- prep: masked copies, chmT, norms, maxpool weighted norms ----
__global__ void prep_kernel(const void* __restrict__ ctx_p,
                            const void* __restrict__ ctx_h,
                            float* __restrict__ ws) {
  int bid = blockIdx.x;
  int side = bid >> 12;        // /4096
  int bl = bid & 4095;
  int b = bl >> 7, l = bl & 127;
  int lane = threadIdx.x;      // 64
  int isb = ws[OFF_FLAG] > 0.5f;
  const void* ctx = side ? ctx_h : ctx_p;
  const float* mask = ws + (side ? OFF_MASKHF : OFF_MASKPF);
  float mk = mask[b * Lc + l];
  size_t rowbase = ((size_t)b * Lc + l) * Hc;
  float* cm = ws + (side ? OFF_CHM : OFF_CPM) + rowbase;

  float v[4];
  float ss = 0.f;
  for (int i = 0; i < 4; i++) {
    int h = lane + 64 * i;
    float x = 0.f;
    if (h < Hc) {
      x = loadf(ctx, rowbase + h, isb) * mk;
      cm[h] = x;
      if (side) ws[OFF_CHMT + ((size_t)b * Hc + h) * Lc + l] = x;
    }
    v[i] = x;
    ss += x * x;
  }
  for (int o = 32; o > 0; o >>= 1) ss += __shfl_xor(ss, o);
  if (lane == 0) ws[(side ? OFF_NORMH : OFF_NORMP) + b * Lc + l] = sqrtf(ss);

  const float* wmpf = ws + OFF_WMP;
  float* nw = ws + (side ? OFF_NWH : OFF_NWP) + (size_t)b * NPc * Lc;
  for (int np_ = 0; np_ < NPc; np_++) {
    float s = 0.f;
    for (int i = 0; i < 4; i++) {
      int h = lane + 64 * i;
      if (h < Hc) {
        float w = wmpf[np_ * Hc + h];
        float wx = w * v[i];
        s += wx * wx;
      }
    }
    for (int o = 32; o > 0; o >>= 1) s += __shfl_xor(s, o);
    if (lane == 0) nw[np_ * Lc + l] = sqrtf(s);
  }
}

// ---------------- lengths + last-token vectors -------------------------------
__global__ void lastlen_kernel(const void* __restrict__ ctx_p,
                               const void* __restrict__ ctx_h,
                               float* __restrict__ ws) {
  int side = blockIdx.x >> 5, b = blockIdx.x & 31;
  int lane = threadIdx.x;  // 64
  int isb = ws[OFF_FLAG] > 0.5f;
  const float* mask = ws + (side ? OFF_MASKHF : OFF_MASKPF);
  const void* ctx = side ? ctx_h : ctx_p;
  float s = 0.f;
  for (int l = lane; l < Lc; l += 64) s += mask[b * Lc + l];
  for (int o = 32; o > 0; o >>= 1) s += __shfl_xor(s, o);
  if (lane == 0) ws[(side ? OFF_LENH : OFF_LENP) + b] = s;
  int idx = (int)(s + 0.5f) - 1;
  if (idx < 0) idx = 0;
  float mk = mask[b * Lc + idx];
  float* lastv = ws + (side ? OFF_LASTH : OFF_LASTP) + (size_t)b * Hc;
  for (int h = lane; h < Hc; h += 64)
    lastv[h] = loadf(ctx, ((size_t)b * Lc + idx) * Hc + h, isb) * mk;
}

// ---------------- cos matrix (and transpose) ---------------------------------
__global__ void cos_kernel(float* __restrict__ ws) {
  int b = blockIdx.x >> 7, p = blockIdx.x & 127;
  int t = threadIdx.x;  // 128
  __shared__ float v1s[Hc];
  for (int h = t; h < Hc; h += 128) v1s[h] = ws[OFF_CPM + ((size_t)b * Lc + p) * Hc + h];
  __syncthreads();
  const float* bT = ws + OFF_CHMT + (size_t)b * Hc * Lc;
  float acc = 0.f;
#pragma unroll 8
  for (int h = 0; h < Hc; h++) acc += v1s[h] * bT[(size_t)h * Lc + t];
  float denom = fmaxf(ws[OFF_NORMP + b * Lc + p] * ws[OFF_NORMH + b * Lc + t], EPSF);
  float cv = acc / denom;
  ws[OFF_COS + ((size_t)b * Lc + p) * Lc + t] = cv;
  ws[OFF_COST + ((size_t)b * Lc + t) * Lc + p] = cv;
}

// ---------------- cos row reductions: channels 0,1 + row/col sums ------------
__global__ void cosred_kernel(const float* __restrict__ rows,
                              const float* __restrict__ maskLoop,
                              const float* __restrict__ maskRow,
                              const float* __restrict__ lenOther,
                              float* __restrict__ sumdst,
                              void* __restrict__ outbase, size_t obase,
                              const float* __restrict__ wsflag) {
  int b = blockIdx.x >> 7, r = blockIdx.x & 127;
  int t = threadIdx.x;  // 128
  int isb = wsflag[0] > 0.5f;
  float c = rows[((size_t)b * Lc + r) * Lc + t];
  float ml = maskLoop[b * Lc + t];
  float mval = (ml > 0.f) ? c : NEGF;
  float sval = c;  // cos at invalid positions is exactly 0
  for (int o = 32; o > 0; o >>= 1) {
    mval = fmaxf(mval, __shfl_xor(mval, o));
    sval += __shfl_xor(sval, o);
  }
  __shared__ float sm[2], ssm[2];
  if ((t & 63) == 0) { sm[t >> 6] = mval; ssm[t >> 6] = sval; }
  __syncthreads();
  if (t == 0) {
    float m = fmaxf(sm[0], sm[1]);
    float s = ssm[0] + ssm[1];
    sumdst[b * Lc + r] = s;
    float mr = maskRow[b * Lc + r];
    size_t orow = obase + ((size_t)b * Lc + r) * NCHc;
    storef(outbase, orow + 0, mr * m, isb);
    storef(outbase, orow + 1, mr * s / fmaxf(mr * lenOther[b], EPSF), isb);
  }
}

// ---------------- fused attentive mean + max (one pass over the other side) --
__global__ void att_kernel(const float* __restrict__ cosrows,
                           const float* __restrict__ vsrc,
                           const float* __restrict__ denom,
                           const float* __restrict__ maskLoop,
                           const float* __restrict__ maskRow,
                           float* __restrict__ amean, float* __restrict__ amax) {
  int b = blockIdx.x >> 7, r = blockIdx.x & 127;
  int t = threadIdx.x;  // 256
  __shared__ float crow[Lc];
  __shared__ float mrow[Lc];
  if (t < Lc) {
    crow[t] = cosrows[((size_t)b * Lc + r) * Lc + t];
    mrow[t] = maskLoop[b * Lc + t];
  }
  __syncthreads();
  if (t < Hc) {
    float s = 0.f, m = NEGF;
    const float* vb = vsrc + (size_t)b * Lc * Hc + t;
#pragma unroll 4
    for (int q = 0; q < Lc; q++) {
      float pr = crow[q] * vb[(size_t)q * Hc];
      s += pr;
      if (mrow[q] > 0.f) m = fmaxf(m, pr);
    }
    float den = fmaxf(denom[b * Lc + r], EPSF);
    amean[((size_t)b * Lc + r) * Hc + t] = s / den;
    amax[((size_t)b * Lc + r) * Hc + t] = maskRow[b * Lc + r] * m;
  }
}

// ---------------- maxpool pairwise: per (b,np) 128x128x200 GEMM + epilogue ---
__global__ __launch_bounds__(256) void maxpool_kernel(
    float* __restrict__ ws, void* __restrict__ out) {
  int np_ = blockIdx.x, b = blockIdx.y;
  int t = threadIdx.x, tx = t & 15, ty = t >> 4;
  int isb = ws[OFF_FLAG] > 0.5f;
  __shared__ float ws2[Hc];
  __shared__ float As[8][132];
  __shared__ float Bs[8][132];
  __shared__ float red[2][128][16];
  for (int h = t; h < Hc; h += 256) {
    float w = ws[OFF_WMP + np_ * Hc + h];
    ws2[h] = w * w;
  }
  const float* A = ws + OFF_CPM + (size_t)b * Lc * Hc;
  const float* Bm = ws + OFF_CHM + (size_t)b * Lc * Hc;
  const float* mask_p = ws + OFF_MASKPF;
  const float* mask_h = ws + OFF_MASKHF;
  float acc[8][8];
#pragma unroll
  for (int i = 0; i < 8; i++)
#pragma unroll
    for (int j = 0; j < 8; j++) acc[i][j] = 0.f;
  __syncthreads();
  for (int hb = 0; hb < Hc; hb += 8) {
    for (int i = t; i < 1024; i += 256) {
      int pp = i >> 3, k = i & 7;
      As[k][pp] = A[(size_t)pp * Hc + hb + k];
    }
    for (int i = t; i < 1024; i += 256) {
      int qq = i >> 3, k = i & 7;
      Bs[k][qq] = ws2[hb + k] * Bm[(size_t)qq * Hc + hb + k];
    }
    __syncthreads();
#pragma unroll
    for (int k = 0; k < 8; k++) {
      float a[8], bb[8];
#pragma unroll
      for (int i = 0; i < 8; i++) a[i] = As[k][ty * 8 + i];
#pragma unroll
      for (int j = 0; j < 8; j++) bb[j] = Bs[k][tx * 8 + j];
#pragma unroll
      for (int i = 0; i < 8; i++)
#pragma unroll
        for (int j = 0; j < 8; j++) acc[i][j] += a[i] * bb[j];
    }
    __syncthreads();
  }
  // epilogue: val = acc/(max(nwp*nwh,eps)); masked max/mean along both axes
  const float* nwp = ws + OFF_NWP + ((size_t)b * NPc + np_) * Lc;
  const float* nwh = ws + OFF_NWH + ((size_t)b * NPc + np_) * Lc;
  float rmax[8], rsum[8], cmax[8], csum[8], mh[8], nh[8];
#pragma unroll
  for (int j = 0; j < 8; j++) {
    mh[j] = mask_h[b * Lc + tx * 8 + j];
    nh[j] = nwh[tx * 8 + j];
    cmax[j] = NEGF;
    csum[j] = 0.f;
  }
#pragma unroll
  for (int i = 0; i < 8; i++) { rmax[i] = NEGF; rsum[i] = 0.f; }
#pragma unroll
  for (int i = 0; i < 8; i++) {
    float npv = nwp[ty * 8 + i];
    float mpv = mask_p[b * Lc + ty * 8 + i];
#pragma unroll
    for (int j = 0; j < 8; j++) {
      float v = acc[i][j] / fmaxf(npv * nh[j], EPSF);
      if (mh[j] > 0.f) rmax[i] = fmaxf(rmax[i], v);
      rsum[i] += v * mh[j];
      if (mpv > 0.f) cmax[j] = fmaxf(cmax[j], v);
      csum[j] += v * mpv;
    }
  }
  float lenp = ws[OFF_LENP + b], lenh = ws[OFF_LENH + b];
  // rows (p side)
#pragma unroll
  for (int i = 0; i < 8; i++) {
    red[0][ty * 8 + i][tx] = rmax[i];
    red[1][ty * 8 + i][tx] = rsum[i];
  }
  __syncthreads();
  if (t < 128) {
    float m = NEGF, s = 0.f;
    for (int x = 0; x < 16; x++) {
      m = fmaxf(m, red[0][t][x]);
      s += red[1][t][x];
    }
    float mpv = mask_p[b * Lc + t];
    size_t orow = ((size_t)b * Lc + t) * NCHc;
    storef(out, orow + 23 + np_, mpv * m, isb);
    storef(out, orow + 43 + np_, mpv * s / fmaxf(mpv * lenh, EPSF), isb);
  }
  __syncthreads();
  // cols (h side)
#pragma unroll
  for (int j = 0; j < 8; j++) {
    red[0][tx * 8 + j][ty] = cmax[j];
    red[1][tx * 8 + j][ty] = csum[j];
  }
  __syncthreads();
  if (t < 128) {
    float m = NEGF, s = 0.f;
    for (int x = 0; x < 16; x++) {
      m = fmaxf(m, red[0][t][x]);
      s += red[1][t][x];
    }
    float mhv = mask_h[b * Lc + t];
    size_t orow = (size_t)Bc * Lc * NCHc + ((size_t)b * Lc + t) * NCHc;
    storef(out, orow + 23 + np_, mhv * m, isb);
    storef(out, orow + 43 + np_, mhv * s / fmaxf(mhv * lenp, EPSF), isb);
  }
}

// ---------------- mpm epilogue: full / attentive / max-attentive channels ----
__global__ __launch_bounds__(256) void mpm_kernel(
    float* __restrict__ ws, void* __restrict__ out) {
  int bid = blockIdx.x;
  int side = bid >> 12;
  int bl = bid & 4095;
  int b = bl >> 7, l = bl & 127;
  int t = threadIdx.x, wv = t >> 6, lane = t & 63;
  int isb = ws[OFF_FLAG] > 0.5f;
  __shared__ float v1s[Hc], v2s[3][Hc];
  __shared__ float n2s[3], dots[3], n1s;
  const float* v1 = ws + (side ? OFF_CHM : OFF_CPM) + ((size_t)b * Lc + l) * Hc;
  const float* v2f = ws + (side ? OFF_LASTP : OFF_LASTH) + (size_t)b * Hc;
  const float* v2a = ws + (side ? OFF_AMEANP : OFF_AMEANH) + ((size_t)b * Lc + l) * Hc;
  const float* v2m = ws + (side ? OFF_AMAXP : OFF_AMAXH) + ((size_t)b * Lc + l) * Hc;
  for (int h = t; h < Hc; h += 256) {
    v1s[h] = v1[h];
    v2s[0][h] = v2f[h];
    v2s[1][h] = v2a[h];
    v2s[2][h] = v2m[h];
  }
  __syncthreads();
  size_t orow = (size_t)side * Bc * Lc * NCHc + ((size_t)b * Lc + l) * NCHc;
  if (wv == 0) {
    float s = 0.f;
    for (int h = lane; h < Hc; h += 64) { float x = v1s[h]; s += x * x; }
    for (int o = 32; o > 0; o >>= 1) s += __shfl_xor(s, o);
    if (lane == 0) n1s = sqrtf(s);
  } else {
    int ty = wv - 1;
    float sd = 0.f, sn = 0.f;
    for (int h = lane; h < Hc; h += 64) {
      float x = v1s[h], y = v2s[ty][h];
      sd += x * y;
      sn += y * y;
    }
    for (int o = 32; o > 0; o >>= 1) {
      sd += __shfl_xor(sd, o);
      sn += __shfl_xor(sn, o);
    }
    if (lane == 0) { dots[ty] = sd; n2s[ty] = sqrtf(sn); }
  }
  __syncthreads();
  if (t < 3) {
    float m1 = dots[t] / fmaxf(n1s * n2s[t], EPSF);
    int ch = (t == 0) ? 2 : ((t == 1) ? 63 : 84);
    storef(out, orow + ch, m1, isb);
  }
  for (int j = wv; j < 60; j += 4) {
    int ty = j / 20, np_ = j % 20;
    const float* w = ws + ((ty == 0) ? OFF_WFULL : ((ty == 1) ? OFF_WATT : OFF_WMATT))
                   + (size_t)np_ * Hc;
    float sd = 0.f, s1 = 0.f, s2 = 0.f;
    for (int h = lane; h < Hc; h += 64) {
      float wq = w[h];
      wq *= wq;
      float x = v1s[h], y = v2s[ty][h];
      sd += wq * x * y;
      s1 += wq * x * x;
      s2 += wq * y * y;
    }
    for (int o = 32; o > 0; o >>= 1) {
      sd += __shfl_xor(sd, o);
      s1 += __shfl_xor(s1, o);
      s2 += __shfl_xor(s2, o);
    }
    if (lane == 0) {
      float mm = sd / fmaxf(sqrtf(s1) * sqrtf(s2), EPSF);
      int ch = ((ty == 0) ? 3 : ((ty == 1) ? 64 : 85)) + np_;
      storef(out, orow + ch, mm, isb);
    }
  }
}

extern "C" void kernel_launch(void* const* d_in, const int* in_sizes, int n_in,
                              void* d_out, int out_size, void* d_ws, size_t ws_size,
                              hipStream_t stream) {
  const void* ctx_p = d_in[0];
  const void* mask_p = d_in[1];
  const void* ctx_h = d_in[2];
  const void* mask_h = d_in[3];
  const void* w_full = d_in[4];
  const void* w_mp = d_in[5];
  const void* w_att = d_in[6];
  const void* w_maxatt = d_in[7];
  float* ws = (float*)d_ws;

  convert_kernel<<<95, 256, 0, stream>>>(mask_p, mask_h, w_full, w_mp, w_att, w_maxatt, ws);
  prep_kernel<<<2 * Bc * Lc, 64, 0, stream>>>(ctx_p, ctx_h, ws);
  lastlen_kernel<<<2 * Bc, 64, 0, stream>>>(ctx_p, ctx_h, ws);
  cos_kernel<<<Bc * Lc, 128, 0, stream>>>(ws);
  cosred_kernel<<<Bc * Lc, 128, 0, stream>>>(ws + OFF_COS, ws + OFF_MASKHF,
                                             ws + OFF_MASKPF, ws + OFF_LENH,
                                             ws + OFF_ROWSUM, d_out, 0, ws + OFF_FLAG);
  cosred_kernel<<<Bc * Lc, 128, 0, stream>>>(ws + OFF_COST, ws + OFF_MASKPF,
                                             ws + OFF_MASKHF, ws + OFF_LENP,
                                             ws + OFF_COLSUM, d_out,
                                             (size_t)Bc * Lc * NCHc, ws + OFF_FLAG);
  att_kernel<<<Bc * Lc, 256, 0, stream>>>(ws + OFF_COS, ws + OFF_CHM, ws + OFF_ROWSUM,
                                          ws + OFF_MASKHF, ws + OFF_MASKPF,
                                          ws + OFF_AMEANH, ws + OFF_AMAXH);
  att_kernel<<<Bc * Lc, 256, 0, stream>>>(ws + OFF_COST, ws + OFF_CPM, ws + OFF_COLSUM,
                                          ws + OFF_MASKPF, ws + OFF_MASKHF,
                                          ws + OFF_AMEANP, ws + OFF_AMAXP);
  maxpool_kernel<<<dim3(NPc, Bc), 256, 0, stream>>>(ws, d_out);
  mpm_kernel<<<2 * Bc * Lc, 256, 0, stream>>>(ws, d_out);
}

// Round 3
// 293.973 us; speedup vs baseline: 1.6240x; 1.6240x over previous
//
#include <hip/hip_runtime.h>
#include <hip/hip_bf16.h>

// BiMPM matching, B=32, L=128, H=200, NP=20.
// Input/output dtype (bf16 vs f32) detected at runtime from mask_p[0] bit
// pattern. All compute in f32 via ws. Output: mv_p (32,128,105), mv_h same.

#define EPSF 1e-8f
#define NEGF -1e7f

constexpr int Bc = 32, Lc = 128, Hc = 200, NPc = 20, NCHc = 105;
constexpr size_t SLH = (size_t)Bc * Lc * Hc;   // 819200
constexpr size_t SLL = (size_t)Bc * Lc * Lc;   // 524288

// workspace layout (floats)
constexpr size_t OFF_CPM    = 0;
constexpr size_t OFF_CHM    = OFF_CPM + SLH;
constexpr size_t OFF_CHMT   = OFF_CHM + SLH;       // [b][h][l]
constexpr size_t OFF_COS    = OFF_CHMT + SLH;      // [b][p][q]
constexpr size_t OFF_COST   = OFF_COS + SLL;       // [b][q][p]
constexpr size_t OFF_AMEANH = OFF_COST + SLL;      // (b,Lp,H)
constexpr size_t OFF_AMAXH  = OFF_AMEANH + SLH;
constexpr size_t OFF_AMEANP = OFF_AMAXH + SLH;     // (b,Lh,H)
constexpr size_t OFF_AMAXP  = OFF_AMEANP + SLH;
constexpr size_t OFF_NORMP  = OFF_AMAXP + SLH;
constexpr size_t OFF_NORMH  = OFF_NORMP + (size_t)Bc * Lc;
constexpr size_t OFF_ROWSUM = OFF_NORMH + (size_t)Bc * Lc;
constexpr size_t OFF_COLSUM = OFF_ROWSUM + (size_t)Bc * Lc;
constexpr size_t OFF_LENP   = OFF_COLSUM + (size_t)Bc * Lc;
constexpr size_t OFF_LENH   = OFF_LENP + Bc;
constexpr size_t OFF_LASTP  = OFF_LENH + Bc;
constexpr size_t OFF_LASTH  = OFF_LASTP + (size_t)Bc * Hc;
constexpr size_t OFF_NWP    = OFF_LASTH + (size_t)Bc * Hc;  // [b][np][l]
constexpr size_t OFF_NWH    = OFF_NWP + (size_t)Bc * NPc * Lc;
constexpr size_t OFF_MASKPF = OFF_NWH + (size_t)Bc * NPc * Lc;
constexpr size_t OFF_MASKHF = OFF_MASKPF + (size_t)Bc * Lc;
constexpr size_t OFF_WFULL  = OFF_MASKHF + (size_t)Bc * Lc;
constexpr size_t OFF_WMP    = OFF_WFULL + (size_t)NPc * Hc;
constexpr size_t OFF_WATT   = OFF_WMP + (size_t)NPc * Hc;
constexpr size_t OFF_WMATT  = OFF_WATT + (size_t)NPc * Hc;
constexpr size_t OFF_FLAG   = OFF_WMATT + (size_t)NPc * Hc;
// new regions
constexpr size_t OFF_WT     = OFF_FLAG + 64;                // [h][64] squared-weights table
constexpr size_t OFF_RPMAX  = OFF_WT + (size_t)Hc * 64;     // [qi][b][np][p]
constexpr size_t OFF_RPSUM  = OFF_RPMAX + 2 * (size_t)Bc * NPc * Lc;
constexpr size_t OFF_CPMAX  = OFF_RPSUM + 2 * (size_t)Bc * NPc * Lc;  // [pi][b][np][q]
constexpr size_t OFF_CPSUM  = OFF_CPMAX + 2 * (size_t)Bc * NPc * Lc;
constexpr size_t WS_FLOATS  = OFF_CPSUM + 2 * (size_t)Bc * NPc * Lc;  // ~7.67M floats (~30.7 MB)

__device__ __forceinline__ float loadf(const void* p, size_t i, int isb) {
  if (isb) return __bfloat162float(((const __hip_bfloat16*)p)[i]);
  return ((const float*)p)[i];
}

__device__ __forceinline__ void storef(void* out, size_t i, float v, int isb) {
  if (isb) ((__hip_bfloat16*)out)[i] = __float2bfloat16(v);
  else ((float*)out)[i] = v;
}

// ---------------- dtype detect + convert small inputs + wT table -------------
__global__ void convert_kernel(const void* mp, const void* mh, const void* wf,
                               const void* wmp, const void* watt, const void* wma,
                               float* __restrict__ ws) {
  int isb = (((const unsigned short*)mp)[0] == 0x3F80u) ? 1 : 0;
  int g = blockIdx.x * 256 + threadIdx.x;
  if (g == 0) ws[OFF_FLAG] = (float)isb;
  const int n0 = Bc * Lc;          // 4096
  const int nw = NPc * Hc;         // 4000
  if (g < n0) {
    ws[OFF_MASKPF + g] = loadf(mp, g, isb);
  } else if (g < 2 * n0) {
    ws[OFF_MASKHF + (g - n0)] = loadf(mh, g - n0, isb);
  } else if (g < 2 * n0 + 4 * nw) {
    int r = g - 2 * n0;
    int seg = r / nw, off = r % nw;
    if (seg == 0) ws[OFF_WFULL + off] = loadf(wf, off, isb);
    else if (seg == 1) ws[OFF_WMP + off] = loadf(wmp, off, isb);
    else if (seg == 2) ws[OFF_WATT + off] = loadf(watt, off, isb);
    else ws[OFF_WMATT + off] = loadf(wma, off, isb);
  } else if (g < 2 * n0 + 4 * nw + Hc * 64) {
    int r = g - (2 * n0 + 4 * nw);
    int h = r >> 6, c = r & 63;
    float w = 1.0f;
    if (c < 20) w = loadf(wf, (size_t)c * Hc + h, isb);
    else if (c < 40) w = loadf(watt, (size_t)(c - 20) * Hc + h, isb);
    else if (c < 60) w = loadf(wma, (size_t)(c - 40) * Hc + h, isb);
    ws[OFF_WT + r] = w * w;
  }
}

// ---------------- prep: masked copies, chmT, norms, maxpool weighted norms ----
__global__ void prep_kernel(const void* __restrict__ ctx_p,
                            const void* __restrict__ ctx_h,
                            float* __restrict__ ws) {
  int bid = blockIdx.x;
  int side = bid >> 12;
  int bl = bid & 4095;
  int b = bl >> 7, l = bl & 127;
  int lane = threadIdx.x;      // 64
  int isb = ws[OFF_FLAG] > 0.5f;
  const void* ctx = side ? ctx_h : ctx_p;
  const float* mask = ws + (side ? OFF_MASKHF : OFF_MASKPF);
  float mk = mask[b * Lc + l];
  size_t rowbase = ((size_t)b * Lc + l) * Hc;
  float* cm = ws + (side ? OFF_CHM : OFF_CPM) + rowbase;

  float v[4];
  float ss = 0.f;
  for (int i = 0; i < 4; i++) {
    int h = lane + 64 * i;
    float x = 0.f;
    if (h < Hc) {
      x = loadf(ctx, rowbase + h, isb) * mk;
      cm[h] = x;
      if (side) ws[OFF_CHMT + ((size_t)b * Hc + h) * Lc + l] = x;
    }
    v[i] = x;
    ss += x * x;
  }
  for (int o = 32; o > 0; o >>= 1) ss += __shfl_xor(ss, o);
  if (lane == 0) ws[(side ? OFF_NORMH : OFF_NORMP) + b * Lc + l] = sqrtf(ss);

  const float* wmpf = ws + OFF_WMP;
  float* nw = ws + (side ? OFF_NWH : OFF_NWP) + (size_t)b * NPc * Lc;
  for (int np_ = 0; np_ < NPc; np_++) {
    float s = 0.f;
    for (int i = 0; i < 4; i++) {
      int h = lane + 64 * i;
      if (h < Hc) {
        float w = wmpf[np_ * Hc + h];
        float wx = w * v[i];
        s += wx * wx;
      }
    }
    for (int o = 32; o > 0; o >>= 1) s += __shfl_xor(s, o);
    if (lane == 0) nw[np_ * Lc + l] = sqrtf(s);
  }
}

// ---------------- lengths + last-token vectors -------------------------------
__global__ void lastlen_kernel(const void* __restrict__ ctx_p,
                               const void* __restrict__ ctx_h,
                               float* __restrict__ ws) {
  int side = blockIdx.x >> 5, b = blockIdx.x & 31;
  int lane = threadIdx.x;  // 64
  int isb = ws[OFF_FLAG] > 0.5f;
  const float* mask = ws + (side ? OFF_MASKHF : OFF_MASKPF);
  const void* ctx = side ? ctx_h : ctx_p;
  float s = 0.f;
  for (int l = lane; l < Lc; l += 64) s += mask[b * Lc + l];
  for (int o = 32; o > 0; o >>= 1) s += __shfl_xor(s, o);
  if (lane == 0) ws[(side ? OFF_LENH : OFF_LENP) + b] = s;
  int idx = (int)(s + 0.5f) - 1;
  if (idx < 0) idx = 0;
  float mk = mask[b * Lc + idx];
  float* lastv = ws + (side ? OFF_LASTH : OFF_LASTP) + (size_t)b * Hc;
  for (int h = lane; h < Hc; h += 64)
    lastv[h] = loadf(ctx, ((size_t)b * Lc + idx) * Hc + h, isb) * mk;
}

// ---------------- cos matrix (and transpose) ---------------------------------
__global__ void cos_kernel(float* __restrict__ ws) {
  int b = blockIdx.x >> 7, p = blockIdx.x & 127;
  int t = threadIdx.x;  // 128
  __shared__ float v1s[Hc];
  for (int h = t; h < Hc; h += 128) v1s[h] = ws[OFF_CPM + ((size_t)b * Lc + p) * Hc + h];
  __syncthreads();
  const float* bT = ws + OFF_CHMT + (size_t)b * Hc * Lc;
  float acc = 0.f;
#pragma unroll 8
  for (int h = 0; h < Hc; h++) acc += v1s[h] * bT[(size_t)h * Lc + t];
  float denom = fmaxf(ws[OFF_NORMP + b * Lc + p] * ws[OFF_NORMH + b * Lc + t], EPSF);
  float cv = acc / denom;
  ws[OFF_COS + ((size_t)b * Lc + p) * Lc + t] = cv;
  ws[OFF_COST + ((size_t)b * Lc + t) * Lc + p] = cv;
}

// ---------------- cos row reductions: channels 0,1 + row/col sums ------------
__global__ void cosred_kernel(const float* __restrict__ rows,
                              const float* __restrict__ maskLoop,
                              const float* __restrict__ maskRow,
                              const float* __restrict__ lenOther,
                              float* __restrict__ sumdst,
                              void* __restrict__ outbase, size_t obase,
                              const float* __restrict__ wsflag) {
  int b = blockIdx.x >> 7, r = blockIdx.x & 127;
  int t = threadIdx.x;  // 128
  int isb = wsflag[0] > 0.5f;
  float c = rows[((size_t)b * Lc + r) * Lc + t];
  float ml = maskLoop[b * Lc + t];
  float mval = (ml > 0.f) ? c : NEGF;
  float sval = c;
  for (int o = 32; o > 0; o >>= 1) {
    mval = fmaxf(mval, __shfl_xor(mval, o));
    sval += __shfl_xor(sval, o);
  }
  __shared__ float sm[2], ssm[2];
  if ((t & 63) == 0) { sm[t >> 6] = mval; ssm[t >> 6] = sval; }
  __syncthreads();
  if (t == 0) {
    float m = fmaxf(sm[0], sm[1]);
    float s = ssm[0] + ssm[1];
    sumdst[b * Lc + r] = s;
    float mr = maskRow[b * Lc + r];
    size_t orow = obase + ((size_t)b * Lc + r) * NCHc;
    storef(outbase, orow + 0, mr * m, isb);
    storef(outbase, orow + 1, mr * s / fmaxf(mr * lenOther[b], EPSF), isb);
  }
}

// ---------------- fused attentive mean + max ---------------------------------
__global__ void att_kernel(const float* __restrict__ cosrows,
                           const float* __restrict__ vsrc,
                           const float* __restrict__ denom,
                           const float* __restrict__ maskLoop,
                           const float* __restrict__ maskRow,
                           float* __restrict__ amean, float* __restrict__ amax) {
  int b = blockIdx.x >> 7, r = blockIdx.x & 127;
  int t = threadIdx.x;  // 256
  __shared__ float crow[Lc];
  __shared__ float mrow[Lc];
  if (t < Lc) {
    crow[t] = cosrows[((size_t)b * Lc + r) * Lc + t];
    mrow[t] = maskLoop[b * Lc + t];
  }
  __syncthreads();
  if (t < Hc) {
    float s = 0.f, m = NEGF;
    const float* vb = vsrc + (size_t)b * Lc * Hc + t;
#pragma unroll 4
    for (int q = 0; q < Lc; q++) {
      float pr = crow[q] * vb[(size_t)q * Hc];
      s += pr;
      if (mrow[q] > 0.f) m = fmaxf(m, pr);
    }
    float den = fmaxf(denom[b * Lc + r], EPSF);
    amean[((size_t)b * Lc + r) * Hc + t] = s / den;
    amax[((size_t)b * Lc + r) * Hc + t] = maskRow[b * Lc + r] * m;
  }
}

// ---------------- maxpool pairwise: 64x64x200 single-wave GEMM + partials ----
__global__ __launch_bounds__(64) void maxpool_kernel(float* __restrict__ ws) {
  int s = blockIdx.x;            // 0..3
  int np_ = blockIdx.y, b = blockIdx.z;
  int pi = s >> 1, qi = s & 1;
  int lane = threadIdx.x;        // 64, single wave
  int tx = lane & 7, ty = lane >> 3;
  __shared__ float w2s[Hc];
  __shared__ float As[8][68];
  __shared__ float Bs[8][68];
  for (int h = lane; h < Hc; h += 64) {
    float w = ws[OFF_WMP + np_ * Hc + h];
    w2s[h] = w * w;
  }
  const float* A = ws + OFF_CPM + ((size_t)b * Lc + pi * 64 + lane) * Hc;
  const float* Bm = ws + OFF_CHM + ((size_t)b * Lc + qi * 64 + lane) * Hc;
  float acc[8][8];
#pragma unroll
  for (int i = 0; i < 8; i++)
#pragma unroll
    for (int j = 0; j < 8; j++) acc[i][j] = 0.f;
  __syncthreads();
  float4 a0 = *(const float4*)(A + 0);
  float4 a1 = *(const float4*)(A + 4);
  float4 b0 = *(const float4*)(Bm + 0);
  float4 b1 = *(const float4*)(Bm + 4);
  for (int hb = 0; hb < Hc; hb += 8) {
    float4 na0, na1, nb0, nb1;
    if (hb + 8 < Hc) {
      na0 = *(const float4*)(A + hb + 8);
      na1 = *(const float4*)(A + hb + 12);
      nb0 = *(const float4*)(Bm + hb + 8);
      nb1 = *(const float4*)(Bm + hb + 12);
    }
    __syncthreads();
    As[0][lane] = a0.x; As[1][lane] = a0.y; As[2][lane] = a0.z; As[3][lane] = a0.w;
    As[4][lane] = a1.x; As[5][lane] = a1.y; As[6][lane] = a1.z; As[7][lane] = a1.w;
    Bs[0][lane] = w2s[hb + 0] * b0.x; Bs[1][lane] = w2s[hb + 1] * b0.y;
    Bs[2][lane] = w2s[hb + 2] * b0.z; Bs[3][lane] = w2s[hb + 3] * b0.w;
    Bs[4][lane] = w2s[hb + 4] * b1.x; Bs[5][lane] = w2s[hb + 5] * b1.y;
    Bs[6][lane] = w2s[hb + 6] * b1.z; Bs[7][lane] = w2s[hb + 7] * b1.w;
    __syncthreads();
#pragma unroll
    for (int k = 0; k < 8; k++) {
      float a[8], bb[8];
#pragma unroll
      for (int i = 0; i < 8; i++) a[i] = As[k][ty * 8 + i];
#pragma unroll
      for (int j = 0; j < 8; j++) bb[j] = Bs[k][tx * 8 + j];
#pragma unroll
      for (int i = 0; i < 8; i++)
#pragma unroll
        for (int j = 0; j < 8; j++) acc[i][j] += a[i] * bb[j];
    }
    a0 = na0; a1 = na1; b0 = nb0; b1 = nb1;
  }
  // epilogue: v = acc * rcp(max(nwp*nwh,eps)); partial masked max/mean both axes
  const float* nwp = ws + OFF_NWP + ((size_t)b * NPc + np_) * Lc + pi * 64;
  const float* nwh = ws + OFF_NWH + ((size_t)b * NPc + np_) * Lc + qi * 64;
  const float* maskP = ws + OFF_MASKPF + b * Lc + pi * 64;
  const float* maskH = ws + OFF_MASKHF + b * Lc + qi * 64;
  float nhv[8], mh[8], cmax[8], csum[8];
#pragma unroll
  for (int j = 0; j < 8; j++) {
    nhv[j] = nwh[tx * 8 + j];
    mh[j] = maskH[tx * 8 + j];
    cmax[j] = NEGF;
    csum[j] = 0.f;
  }
  float rmax[8], rsum[8];
#pragma unroll
  for (int i = 0; i < 8; i++) {
    rmax[i] = NEGF;
    rsum[i] = 0.f;
    float npv = nwp[ty * 8 + i];
    float mpv = maskP[ty * 8 + i];
#pragma unroll
    for (int j = 0; j < 8; j++) {
      float v = acc[i][j] * __builtin_amdgcn_rcpf(fmaxf(npv * nhv[j], EPSF));
      if (mh[j] > 0.f) rmax[i] = fmaxf(rmax[i], v);
      rsum[i] += v * mh[j];
      if (mpv > 0.f) cmax[j] = fmaxf(cmax[j], v);
      csum[j] += v * mpv;
    }
  }
  // cross-lane: rows over tx (bits 0-2), cols over ty (bits 3-5)
#pragma unroll
  for (int o = 1; o <= 4; o <<= 1) {
#pragma unroll
    for (int i = 0; i < 8; i++) {
      rmax[i] = fmaxf(rmax[i], __shfl_xor(rmax[i], o));
      rsum[i] += __shfl_xor(rsum[i], o);
    }
  }
#pragma unroll
  for (int o = 8; o <= 32; o <<= 1) {
#pragma unroll
    for (int j = 0; j < 8; j++) {
      cmax[j] = fmaxf(cmax[j], __shfl_xor(cmax[j], o));
      csum[j] += __shfl_xor(csum[j], o);
    }
  }
  size_t rp = OFF_RPMAX - OFF_RPMAX; // silence unused warn pattern
  (void)rp;
  size_t rbase = (((size_t)qi * Bc + b) * NPc + np_) * Lc + pi * 64;
  size_t cbase = (((size_t)pi * Bc + b) * NPc + np_) * Lc + qi * 64;
  if (tx == 0) {
#pragma unroll
    for (int i = 0; i < 8; i++) {
      ws[OFF_RPMAX + rbase + ty * 8 + i] = rmax[i];
      ws[OFF_RPSUM + rbase + ty * 8 + i] = rsum[i];
    }
  }
  if (ty == 0) {
#pragma unroll
    for (int j = 0; j < 8; j++) {
      ws[OFF_CPMAX + cbase + tx * 8 + j] = cmax[j];
      ws[OFF_CPSUM + cbase + tx * 8 + j] = csum[j];
    }
  }
}

// ---------------- maxpool finalize: combine 2 partials, write channels -------
__global__ void mpfin_kernel(float* __restrict__ ws, void* __restrict__ out) {
  int g = blockIdx.x * 256 + threadIdx.x;  // 2*32*20*128 = 163840
  if (g >= 2 * Bc * NPc * Lc) return;
  int isb = ws[OFF_FLAG] > 0.5f;
  int l = g & 127;
  int r = g >> 7;
  int np_ = r % NPc;
  int t2 = r / NPc;
  int b = t2 & 31;
  int side = t2 >> 5;
  size_t i0 = (((size_t)0 * Bc + b) * NPc + np_) * Lc + l;
  size_t i1 = (((size_t)1 * Bc + b) * NPc + np_) * Lc + l;
  float m, sum, mk, len;
  if (side == 0) {
    m = fmaxf(ws[OFF_RPMAX + i0], ws[OFF_RPMAX + i1]);
    sum = ws[OFF_RPSUM + i0] + ws[OFF_RPSUM + i1];
    mk = ws[OFF_MASKPF + b * Lc + l];
    len = ws[OFF_LENH + b];
  } else {
    m = fmaxf(ws[OFF_CPMAX + i0], ws[OFF_CPMAX + i1]);
    sum = ws[OFF_CPSUM + i0] + ws[OFF_CPSUM + i1];
    mk = ws[OFF_MASKHF + b * Lc + l];
    len = ws[OFF_LENP + b];
  }
  size_t orow = (size_t)side * Bc * Lc * NCHc + ((size_t)b * Lc + l) * NCHc;
  storef(out, orow + 23 + np_, mk * m, isb);
  storef(out, orow + 43 + np_, mk * sum / fmaxf(mk * len, EPSF), isb);
}

// ---------------- mpm epilogue: lane-per-channel, no cross-lane --------------
__global__ __launch_bounds__(64) void mpm_kernel(float* __restrict__ ws,
                                                 void* __restrict__ out) {
  int bid = blockIdx.x;
  int side = bid >> 12;
  int b = (bid >> 7) & 31, l = bid & 127;
  int c = threadIdx.x;  // 64: lane = channel
  int isb = ws[OFF_FLAG] > 0.5f;
  __shared__ float v1s[Hc];
  __shared__ float v2s[3][Hc];
  const float* v1 = ws + (side ? OFF_CHM : OFF_CPM) + ((size_t)b * Lc + l) * Hc;
  const float* v2f = ws + (side ? OFF_LASTP : OFF_LASTH) + (size_t)b * Hc;
  const float* v2a = ws + (side ? OFF_AMEANP : OFF_AMEANH) + ((size_t)b * Lc + l) * Hc;
  const float* v2m = ws + (side ? OFF_AMAXP : OFF_AMAXH) + ((size_t)b * Lc + l) * Hc;
  for (int h = c; h < Hc; h += 64) {
    v1s[h] = v1[h];
    v2s[0][h] = v2f[h];
    v2s[1][h] = v2a[h];
    v2s[2][h] = v2m[h];
  }
  __syncthreads();
  int v2i = (c < 20) ? 0 : (c < 40) ? 1 : (c < 60) ? 2 : (c - 60);
  if (v2i > 2) v2i = 2;
  const float* yv = v2s[v2i];
  const float* wt = ws + OFF_WT + c;
  float sd = 0.f, s1 = 0.f, s2 = 0.f;
#pragma unroll 4
  for (int h = 0; h < Hc; h++) {
    float wq = wt[(size_t)h * 64];
    float x = v1s[h], y = yv[h];
    float t1 = wq * x, t2 = wq * y;
    sd += t1 * y;
    s1 += t1 * x;
    s2 += t2 * y;
  }
  float mm = sd / fmaxf(sqrtf(s1) * sqrtf(s2), EPSF);
  int ch;
  if (c < 20) ch = 3 + c;
  else if (c < 40) ch = 64 + (c - 20);
  else if (c < 60) ch = 85 + (c - 40);
  else if (c == 60) ch = 2;
  else if (c == 61) ch = 63;
  else if (c == 62) ch = 84;
  else ch = -1;
  if (ch >= 0) {
    size_t orow = (size_t)side * Bc * Lc * NCHc + ((size_t)b * Lc + l) * NCHc;
    storef(out, orow + ch, mm, isb);
  }
}

extern "C" void kernel_launch(void* const* d_in, const int* in_sizes, int n_in,
                              void* d_out, int out_size, void* d_ws, size_t ws_size,
                              hipStream_t stream) {
  const void* ctx_p = d_in[0];
  const void* mask_p = d_in[1];
  const void* ctx_h = d_in[2];
  const void* mask_h = d_in[3];
  const void* w_full = d_in[4];
  const void* w_mp = d_in[5];
  const void* w_att = d_in[6];
  const void* w_maxatt = d_in[7];
  float* ws = (float*)d_ws;

  convert_kernel<<<145, 256, 0, stream>>>(mask_p, mask_h, w_full, w_mp, w_att, w_maxatt, ws);
  prep_kernel<<<2 * Bc * Lc, 64, 0, stream>>>(ctx_p, ctx_h, ws);
  lastlen_kernel<<<2 * Bc, 64, 0, stream>>>(ctx_p, ctx_h, ws);
  cos_kernel<<<Bc * Lc, 128, 0, stream>>>(ws);
  cosred_kernel<<<Bc * Lc, 128, 0, stream>>>(ws + OFF_COS, ws + OFF_MASKHF,
                                             ws + OFF_MASKPF, ws + OFF_LENH,
                                             ws + OFF_ROWSUM, d_out, 0, ws + OFF_FLAG);
  cosred_kernel<<<Bc * Lc, 128, 0, stream>>>(ws + OFF_COST, ws + OFF_MASKPF,
                                             ws + OFF_MASKHF, ws + OFF_LENP,
                                             ws + OFF_COLSUM, d_out,
                                             (size_t)Bc * Lc * NCHc, ws + OFF_FLAG);
  att_kernel<<<Bc * Lc, 256, 0, stream>>>(ws + OFF_COS, ws + OFF_CHM, ws + OFF_ROWSUM,
                                          ws + OFF_MASKHF, ws + OFF_MASKPF,
                                          ws + OFF_AMEANH, ws + OFF_AMAXH);
  att_kernel<<<Bc * Lc, 256, 0, stream>>>(ws + OFF_COST, ws + OFF_CPM, ws + OFF_COLSUM,
                                          ws + OFF_MASKPF, ws + OFF_MASKHF,
                                          ws + OFF_AMEANP, ws + OFF_AMAXP);
  maxpool_kernel<<<dim3(4, NPc, Bc), 64, 0, stream>>>(ws);
  mpfin_kernel<<<640, 256, 0, stream>>>(ws, d_out);
  mpm_kernel<<<2 * Bc * Lc, 64, 0, stream>>>(ws, d_out);
}